// Round 1
// baseline (740.056 us; speedup 1.0000x reference)
//
#include <hip/hip_runtime.h>

#define B_ 16
#define N_ 10000
#define H_ 128
#define E_ 320000
#define R_ (B_ * N_)   // 160000 rows total
#define MT 32          // nodes per MLP block

// ---------------- CSR build ----------------
__global__ void hist_kernel(const int* __restrict__ dst, int* __restrict__ counts) {
    int e = blockIdx.x * blockDim.x + threadIdx.x;
    if (e < E_) atomicAdd(&counts[dst[e]], 1);
}

__global__ void scan_kernel(const int* __restrict__ counts, int* __restrict__ offsets,
                            int* __restrict__ cursor) {
    __shared__ int sums[256];
    int t = threadIdx.x;
    const int chunk = (N_ + 255) / 256;  // 40
    int lo = t * chunk;
    int hi = min(lo + chunk, N_);
    int s = 0;
    for (int i = lo; i < hi; ++i) s += counts[i];
    sums[t] = s;
    __syncthreads();
    // Hillis-Steele inclusive scan over 256 partials
    for (int off = 1; off < 256; off <<= 1) {
        int add = (t >= off) ? sums[t - off] : 0;
        __syncthreads();
        sums[t] += add;
        __syncthreads();
    }
    int run = (t == 0) ? 0 : sums[t - 1];
    for (int i = lo; i < hi; ++i) {
        int c = counts[i];
        offsets[i] = run;
        cursor[i] = run;
        run += c;
    }
    if (t == 255) offsets[N_] = run;  // == E_
}

__global__ void fill_kernel(const int* __restrict__ src, const int* __restrict__ dst,
                            int* __restrict__ cursor, int* __restrict__ srcs_sorted) {
    int e = blockIdx.x * blockDim.x + threadIdx.x;
    if (e < E_) {
        int d = dst[e];
        int pos = atomicAdd(&cursor[d], 1);
        srcs_sorted[pos] = src[e];
    }
}

// ---------------- segment-sum via gather (no atomics on the big array) ----------------
// grid = (N/8, B), block = 256. Thread handles (node, h4) for one batch.
// 32 consecutive lanes read consecutive float4 of the same source row -> coalesced 512B.
__global__ __launch_bounds__(256) void gather_kernel(
        const float4* __restrict__ emb4, const int* __restrict__ offsets,
        const int* __restrict__ srcs, float4* __restrict__ nb4) {
    int n  = blockIdx.x * 8 + (threadIdx.x >> 5);
    int h4 = threadIdx.x & 31;
    int b  = blockIdx.y;
    int beg = offsets[n], end = offsets[n + 1];
    const float4* sb = emb4 + (size_t)b * N_ * 32;
    float4 acc = make_float4(0.f, 0.f, 0.f, 0.f);
    for (int e = beg; e < end; ++e) {
        int s = srcs[e];
        float4 v = sb[(size_t)s * 32 + h4];
        acc.x += v.x; acc.y += v.y; acc.z += v.z; acc.w += v.w;
    }
    nb4[((size_t)b * N_ + n) * 32 + h4] = acc;
}

// ---------------- fused 2-layer MLP + mask select ----------------
// block = 256 threads, MT=32 rows (flat r = b*N + n; layouts are flat [R][128] so
// tiles may cross batch boundaries safely). LDS: ctx 32x260 (pad kills bank
// conflicts: bank = (row*4 + f) % 32), hbuf 32x132. ~50KB -> 3 blocks/CU.
__global__ __launch_bounds__(256) void mlp_kernel(
        const float* __restrict__ nb, const float* __restrict__ emb,
        const int* __restrict__ mask,
        const float* __restrict__ W1, const float* __restrict__ b1,
        const float* __restrict__ W2, const float* __restrict__ b2,
        float* __restrict__ out) {
    __shared__ __align__(16) float ctx[MT][260];
    __shared__ __align__(16) float hbuf[MT][132];
    int tx = threadIdx.x;
    size_t tile = (size_t)blockIdx.x * MT;

    // stage context tile: 32 rows x 256 floats = 2048 float4, 8 per thread
    const float4* nb4  = (const float4*)nb;
    const float4* emb4 = (const float4*)emb;
#pragma unroll
    for (int k = 0; k < 8; ++k) {
        int q = tx + k * 256;
        int row = q >> 6, c4 = q & 63;
        size_t r = tile + row;
        float4 v = (c4 < 32) ? nb4[r * 32 + c4] : emb4[r * 32 + (c4 - 32)];
        *(float4*)&ctx[row][c4 * 4] = v;
    }
    __syncthreads();

    int hq = tx & 31;   // output features hq*4 .. hq*4+3
    int mq = tx >> 5;   // rows mq*4 .. mq*4+3

    // ---- layer 1: h = relu(ctx @ W1 + b1) ----
    float acc[4][4];
    float4 bb = *(const float4*)&b1[hq * 4];
#pragma unroll
    for (int i = 0; i < 4; ++i) {
        acc[i][0] = bb.x; acc[i][1] = bb.y; acc[i][2] = bb.z; acc[i][3] = bb.w;
    }
#pragma unroll 4
    for (int f = 0; f < 256; ++f) {
        float4 w = *(const float4*)&W1[f * 128 + hq * 4];
#pragma unroll
        for (int i = 0; i < 4; ++i) {
            float c = ctx[mq * 4 + i][f];
            acc[i][0] = fmaf(c, w.x, acc[i][0]);
            acc[i][1] = fmaf(c, w.y, acc[i][1]);
            acc[i][2] = fmaf(c, w.z, acc[i][2]);
            acc[i][3] = fmaf(c, w.w, acc[i][3]);
        }
    }
#pragma unroll
    for (int i = 0; i < 4; ++i) {
        float4 hv = make_float4(fmaxf(acc[i][0], 0.f), fmaxf(acc[i][1], 0.f),
                                fmaxf(acc[i][2], 0.f), fmaxf(acc[i][3], 0.f));
        *(float4*)&hbuf[mq * 4 + i][hq * 4] = hv;
    }
    __syncthreads();

    // ---- layer 2: imputed = h @ W2 + b2 ----
    float acc2[4][4];
    float4 bb2 = *(const float4*)&b2[hq * 4];
#pragma unroll
    for (int i = 0; i < 4; ++i) {
        acc2[i][0] = bb2.x; acc2[i][1] = bb2.y; acc2[i][2] = bb2.z; acc2[i][3] = bb2.w;
    }
#pragma unroll 4
    for (int k = 0; k < 128; ++k) {
        float4 w = *(const float4*)&W2[k * 128 + hq * 4];
#pragma unroll
        for (int i = 0; i < 4; ++i) {
            float hv = hbuf[mq * 4 + i][k];
            acc2[i][0] = fmaf(hv, w.x, acc2[i][0]);
            acc2[i][1] = fmaf(hv, w.y, acc2[i][1]);
            acc2[i][2] = fmaf(hv, w.z, acc2[i][2]);
            acc2[i][3] = fmaf(hv, w.w, acc2[i][3]);
        }
    }

    // ---- epilogue: out = mask ? imputed : emb (emb still in ctx[:,128:256]) ----
    float4* out4 = (float4*)out;
#pragma unroll
    for (int i = 0; i < 4; ++i) {
        size_t r = tile + mq * 4 + i;
        int m = mask[r];
        float4 o;
        if (m) {
            o = make_float4(acc2[i][0], acc2[i][1], acc2[i][2], acc2[i][3]);
        } else {
            o = *(const float4*)&ctx[mq * 4 + i][128 + hq * 4];
        }
        out4[r * 32 + hq] = o;
    }
}

extern "C" void kernel_launch(void* const* d_in, const int* in_sizes, int n_in,
                              void* d_out, int out_size, void* d_ws, size_t ws_size,
                              hipStream_t stream) {
    const float* emb  = (const float*)d_in[0];   // (B,N,H) f32
    const int*   mask = (const int*)d_in[1];     // (B,N) i32
    const int*   eidx = (const int*)d_in[2];     // (2,E) i32
    const float* W1   = (const float*)d_in[3];   // (256,128)
    const float* b1   = (const float*)d_in[4];   // (128)
    const float* W2   = (const float*)d_in[5];   // (128,128)
    const float* b2   = (const float*)d_in[6];   // (128)
    float* out = (float*)d_out;

    const int* src = eidx;
    const int* dst = eidx + E_;

    // workspace layout (ws re-poisoned each call; everything below is
    // either memset here or fully overwritten before being read)
    char* ws = (char*)d_ws;
    float* nb = (float*)ws;                                // 81,920,000 B
    size_t o = (size_t)R_ * H_ * sizeof(float);
    int* counts  = (int*)(ws + o);            o += 40064;  // N ints
    int* offsets = (int*)(ws + o);            o += 40064;  // N+1 ints
    int* cursor  = (int*)(ws + o);            o += 40064;  // N ints
    int* srcs    = (int*)(ws + o);                         // E ints

    hipMemsetAsync(counts, 0, N_ * sizeof(int), stream);
    hist_kernel<<<E_ / 256, 256, 0, stream>>>(dst, counts);
    scan_kernel<<<1, 256, 0, stream>>>(counts, offsets, cursor);
    fill_kernel<<<E_ / 256, 256, 0, stream>>>(src, dst, cursor, srcs);
    gather_kernel<<<dim3(N_ / 8, B_), 256, 0, stream>>>(
        (const float4*)emb, offsets, srcs, (float4*)nb);
    mlp_kernel<<<R_ / MT, 256, 0, stream>>>(nb, emb, mask, W1, b1, W2, b2, out);
}

// Round 2
// 576.385 us; speedup vs baseline: 1.2840x; 1.2840x over previous
//
#include <hip/hip_runtime.h>

#define B_ 16
#define N_ 10000
#define H_ 128
#define E_ 320000
#define R_ (B_ * N_)   // 160000 rows
#define MT 32          // rows per MLP block

// ---------------- fp32 -> bf16 (RNE) conversion of node_embeddings ----------------
__global__ __launch_bounds__(256) void cvt_bf16_kernel(const float4* __restrict__ in4,
                                                       uint4* __restrict__ out4) {
    int t = blockIdx.x * 256 + threadIdx.x;      // handles 8 floats
    float4 a = in4[t * 2 + 0];
    float4 b = in4[t * 2 + 1];
    const float* f = (const float*)&a;
    const float* g = (const float*)&b;
    uint r[8];
#pragma unroll
    for (int i = 0; i < 4; ++i) {
        uint u = __float_as_uint(f[i]);
        r[i] = (u + 0x7fffu + ((u >> 16) & 1u)) >> 16;
    }
#pragma unroll
    for (int i = 0; i < 4; ++i) {
        uint u = __float_as_uint(g[i]);
        r[4 + i] = (u + 0x7fffu + ((u >> 16) & 1u)) >> 16;
    }
    uint4 o;
    o.x = r[0] | (r[1] << 16);
    o.y = r[2] | (r[3] << 16);
    o.z = r[4] | (r[5] << 16);
    o.w = r[6] | (r[7] << 16);
    out4[t] = o;
}

// ---------------- CSR build ----------------
__global__ void hist_kernel(const int* __restrict__ dst, int* __restrict__ counts) {
    int e = blockIdx.x * blockDim.x + threadIdx.x;
    if (e < E_) atomicAdd(&counts[dst[e]], 1);
}

__global__ __launch_bounds__(1024) void scan_kernel(const int* __restrict__ counts,
                                                    int* __restrict__ offsets,
                                                    int* __restrict__ cursor) {
    __shared__ int sums[1024];
    int t = threadIdx.x;
    const int chunk = (N_ + 1023) / 1024;  // 10
    int lo = t * chunk;
    int hi = min(lo + chunk, N_);
    int s = 0;
    for (int i = lo; i < hi; ++i) s += counts[i];
    sums[t] = s;
    __syncthreads();
    for (int off = 1; off < 1024; off <<= 1) {
        int add = (t >= off) ? sums[t - off] : 0;
        __syncthreads();
        sums[t] += add;
        __syncthreads();
    }
    int run = (t == 0) ? 0 : sums[t - 1];
    for (int i = lo; i < hi; ++i) {
        int c = counts[i];
        offsets[i] = run;
        cursor[i] = run;
        run += c;
    }
    if (t == 1023) offsets[N_] = run;  // == E_
}

__global__ void fill_kernel(const int* __restrict__ src, const int* __restrict__ dst,
                            int* __restrict__ cursor, int* __restrict__ srcs_sorted) {
    int e = blockIdx.x * blockDim.x + threadIdx.x;
    if (e < E_) {
        int d = dst[e];
        int pos = atomicAdd(&cursor[d], 1);
        srcs_sorted[pos] = src[e];
    }
}

// ---------------- segment-sum gather, bf16 source, fp32 accumulate ----------------
// 16 nodes/block (16 lanes x 16B each). XCD-affine: bid%8 -> XCD -> batch pair,
// first all idx<625 blocks (batch 2x: 2.56MB bf16, L2-resident), then batch 2x+1.
__global__ __launch_bounds__(256) void gather_bf16_kernel(
        const uint4* __restrict__ ebf4, const int* __restrict__ offsets,
        const int* __restrict__ srcs, float4* __restrict__ nb4) {
    int bid = blockIdx.x;
    int xcd = bid & 7;
    int idx = bid >> 3;           // 0..1249
    int half = (idx >= 625) ? 1 : 0;
    int b = xcd * 2 + half;
    int ng = idx - half * 625;
    int n = ng * 16 + (threadIdx.x >> 4);
    int lane = threadIdx.x & 15;  // features lane*8 .. lane*8+7
    int beg = offsets[n], end = offsets[n + 1];
    const uint4* sb = ebf4 + (size_t)b * N_ * 16;
    float acc[8] = {0.f, 0.f, 0.f, 0.f, 0.f, 0.f, 0.f, 0.f};
    for (int e = beg; e < end; ++e) {
        int s = srcs[e];
        uint4 v = sb[(size_t)s * 16 + lane];
        acc[0] += __uint_as_float(v.x << 16);
        acc[1] += __uint_as_float(v.x & 0xffff0000u);
        acc[2] += __uint_as_float(v.y << 16);
        acc[3] += __uint_as_float(v.y & 0xffff0000u);
        acc[4] += __uint_as_float(v.z << 16);
        acc[5] += __uint_as_float(v.z & 0xffff0000u);
        acc[6] += __uint_as_float(v.w << 16);
        acc[7] += __uint_as_float(v.w & 0xffff0000u);
    }
    size_t r = (size_t)b * N_ + n;
    nb4[r * 32 + lane * 2 + 0] = make_float4(acc[0], acc[1], acc[2], acc[3]);
    nb4[r * 32 + lane * 2 + 1] = make_float4(acc[4], acc[5], acc[6], acc[7]);
}

// fp32 fallback gather (used only if ws too small for the bf16 copy)
__global__ __launch_bounds__(256) void gather_kernel(
        const float4* __restrict__ emb4, const int* __restrict__ offsets,
        const int* __restrict__ srcs, float4* __restrict__ nb4) {
    int n  = blockIdx.x * 8 + (threadIdx.x >> 5);
    int h4 = threadIdx.x & 31;
    int b  = blockIdx.y;
    int beg = offsets[n], end = offsets[n + 1];
    const float4* sb = emb4 + (size_t)b * N_ * 32;
    float4 acc = make_float4(0.f, 0.f, 0.f, 0.f);
    for (int e = beg; e < end; ++e) {
        int s = srcs[e];
        float4 v = sb[(size_t)s * 32 + h4];
        acc.x += v.x; acc.y += v.y; acc.z += v.z; acc.w += v.w;
    }
    nb4[((size_t)b * N_ + n) * 32 + h4] = acc;
}

// ---------------- fused 2-layer MLP + mask select ----------------
// 256 threads, 32 rows. ctx[32][260] (stride 1040B: 16B-aligned, +4 dword skew).
// h overlaid into ctx[:,0:128] after layer 1 (region dead once W1 pass done).
// LDS 33.3KB -> 4 blocks/CU -> 16 waves/CU. Inner loop: b128 broadcast ctx reads.
__global__ __launch_bounds__(256) void mlp_kernel(
        const float* __restrict__ nb, const float* __restrict__ emb,
        const int* __restrict__ mask,
        const float* __restrict__ W1, const float* __restrict__ b1,
        const float* __restrict__ W2, const float* __restrict__ b2,
        float* __restrict__ out) {
    __shared__ __align__(16) float ctx[MT][260];
    int tx = threadIdx.x;
    size_t tile = (size_t)blockIdx.x * MT;

    const float4* nb4  = (const float4*)nb;
    const float4* emb4 = (const float4*)emb;
#pragma unroll
    for (int k = 0; k < 8; ++k) {
        int q = tx + k * 256;
        int row = q >> 6, c4 = q & 63;
        size_t r = tile + row;
        float4 v = (c4 < 32) ? nb4[r * 32 + c4] : emb4[r * 32 + (c4 - 32)];
        *(float4*)&ctx[row][c4 * 4] = v;
    }
    __syncthreads();

    int hq = tx & 31;   // feature quad
    int mq = tx >> 5;   // row quad

    const float4* W1r = (const float4*)W1;
    const float4* W2r = (const float4*)W2;

    // ---- layer 1: h = relu(ctx @ W1 + b1) ----
    float4 acc[4];
    {
        float4 bb = *(const float4*)&b1[hq * 4];
#pragma unroll
        for (int i = 0; i < 4; ++i) acc[i] = bb;
    }
#pragma unroll 2
    for (int k = 0; k < 256; k += 4) {
        float4 w0 = W1r[(k + 0) * 32 + hq];
        float4 w1 = W1r[(k + 1) * 32 + hq];
        float4 w2 = W1r[(k + 2) * 32 + hq];
        float4 w3 = W1r[(k + 3) * 32 + hq];
#pragma unroll
        for (int i = 0; i < 4; ++i) {
            float4 c = *(const float4*)&ctx[mq * 4 + i][k];
            acc[i].x = fmaf(c.x, w0.x, fmaf(c.y, w1.x, fmaf(c.z, w2.x, fmaf(c.w, w3.x, acc[i].x))));
            acc[i].y = fmaf(c.x, w0.y, fmaf(c.y, w1.y, fmaf(c.z, w2.y, fmaf(c.w, w3.y, acc[i].y))));
            acc[i].z = fmaf(c.x, w0.z, fmaf(c.y, w1.z, fmaf(c.z, w2.z, fmaf(c.w, w3.z, acc[i].z))));
            acc[i].w = fmaf(c.x, w0.w, fmaf(c.y, w1.w, fmaf(c.z, w2.w, fmaf(c.w, w3.w, acc[i].w))));
        }
    }
    __syncthreads();   // everyone done reading ctx[:,0:256] for layer 1
#pragma unroll
    for (int i = 0; i < 4; ++i) {
        float4 hv = make_float4(fmaxf(acc[i].x, 0.f), fmaxf(acc[i].y, 0.f),
                                fmaxf(acc[i].z, 0.f), fmaxf(acc[i].w, 0.f));
        *(float4*)&ctx[mq * 4 + i][hq * 4] = hv;   // h overlay into [:,0:128]
    }
    __syncthreads();

    // ---- layer 2: imputed = h @ W2 + b2 ----
    float4 acc2[4];
    {
        float4 bb2 = *(const float4*)&b2[hq * 4];
#pragma unroll
        for (int i = 0; i < 4; ++i) acc2[i] = bb2;
    }
#pragma unroll 2
    for (int k = 0; k < 128; k += 4) {
        float4 w0 = W2r[(k + 0) * 32 + hq];
        float4 w1 = W2r[(k + 1) * 32 + hq];
        float4 w2 = W2r[(k + 2) * 32 + hq];
        float4 w3 = W2r[(k + 3) * 32 + hq];
#pragma unroll
        for (int i = 0; i < 4; ++i) {
            float4 c = *(const float4*)&ctx[mq * 4 + i][k];
            acc2[i].x = fmaf(c.x, w0.x, fmaf(c.y, w1.x, fmaf(c.z, w2.x, fmaf(c.w, w3.x, acc2[i].x))));
            acc2[i].y = fmaf(c.x, w0.y, fmaf(c.y, w1.y, fmaf(c.z, w2.y, fmaf(c.w, w3.y, acc2[i].y))));
            acc2[i].z = fmaf(c.x, w0.z, fmaf(c.y, w1.z, fmaf(c.z, w2.z, fmaf(c.w, w3.z, acc2[i].z))));
            acc2[i].w = fmaf(c.x, w0.w, fmaf(c.y, w1.w, fmaf(c.z, w2.w, fmaf(c.w, w3.w, acc2[i].w))));
        }
    }

    // ---- epilogue: out = mask ? imputed : emb (emb intact in ctx[:,128:256]) ----
    float4* out4 = (float4*)out;
#pragma unroll
    for (int i = 0; i < 4; ++i) {
        size_t r = tile + mq * 4 + i;
        int m = mask[r];
        float4 o;
        if (m) {
            o = acc2[i];
        } else {
            o = *(const float4*)&ctx[mq * 4 + i][128 + hq * 4];
        }
        out4[r * 32 + hq] = o;
    }
}

extern "C" void kernel_launch(void* const* d_in, const int* in_sizes, int n_in,
                              void* d_out, int out_size, void* d_ws, size_t ws_size,
                              hipStream_t stream) {
    const float* emb  = (const float*)d_in[0];   // (B,N,H) f32
    const int*   mask = (const int*)d_in[1];     // (B,N) i32
    const int*   eidx = (const int*)d_in[2];     // (2,E) i32
    const float* W1   = (const float*)d_in[3];   // (256,128)
    const float* b1   = (const float*)d_in[4];   // (128)
    const float* W2   = (const float*)d_in[5];   // (128,128)
    const float* b2   = (const float*)d_in[6];   // (128)
    float* out = (float*)d_out;

    const int* src = eidx;
    const int* dst = eidx + E_;

    char* ws = (char*)d_ws;
    size_t o = 0;
    float* nb = (float*)(ws + o);   o += (size_t)R_ * H_ * sizeof(float);    // 81.92 MB
    unsigned short* ebf = (unsigned short*)(ws + o);
    size_t o_bf_end = o + (size_t)R_ * H_ * sizeof(unsigned short);          // +40.96 MB
    bool use_bf16 = (ws_size >= o_bf_end + 3 * 40064 + (size_t)E_ * 4);
    if (use_bf16) o = o_bf_end;
    int* counts  = (int*)(ws + o);  o += 40064;  // N ints (padded)
    int* offsets = (int*)(ws + o);  o += 40064;  // N+1 ints
    int* cursor  = (int*)(ws + o);  o += 40064;  // N ints
    int* srcs    = (int*)(ws + o);               // E ints

    hipMemsetAsync(counts, 0, N_ * sizeof(int), stream);
    if (use_bf16) {
        cvt_bf16_kernel<<<R_ * H_ / (256 * 8), 256, 0, stream>>>(
            (const float4*)emb, (uint4*)ebf);
    }
    hist_kernel<<<E_ / 256, 256, 0, stream>>>(dst, counts);
    scan_kernel<<<1, 1024, 0, stream>>>(counts, offsets, cursor);
    fill_kernel<<<E_ / 256, 256, 0, stream>>>(src, dst, cursor, srcs);
    if (use_bf16) {
        gather_bf16_kernel<<<B_ * N_ / 16, 256, 0, stream>>>(
            (const uint4*)ebf, offsets, srcs, (float4*)nb);
    } else {
        gather_kernel<<<dim3(N_ / 8, B_), 256, 0, stream>>>(
            (const float4*)emb, offsets, srcs, (float4*)nb);
    }
    mlp_kernel<<<R_ / MT, 256, 0, stream>>>(nb, emb, mask, W1, b1, W2, b2, out);
}

// Round 4
// 475.795 us; speedup vs baseline: 1.5554x; 1.2114x over previous
//
#include <hip/hip_runtime.h>

#define B_ 16
#define N_ 10000
#define H_ 128
#define E_ 320000
#define R_ (B_ * N_)   // 160000 rows
#define LDC 264        // ctx LDS row stride in bf16 units (256 data + 8 pad)

typedef __attribute__((ext_vector_type(8))) short bf16x8;
typedef __attribute__((ext_vector_type(4))) float f32x4;

static __device__ __forceinline__ unsigned short f2bf(float f) {
    unsigned int u = __float_as_uint(f);
    return (unsigned short)((u + 0x7fffu + ((u >> 16) & 1u)) >> 16);
}

// ---------------- fp32 -> bf16 (RNE) conversion of node_embeddings ----------------
__global__ __launch_bounds__(256) void cvt_bf16_kernel(const float4* __restrict__ in4,
                                                       uint4* __restrict__ out4) {
    int t = blockIdx.x * 256 + threadIdx.x;      // handles 8 floats
    float4 a = in4[t * 2 + 0];
    float4 b = in4[t * 2 + 1];
    unsigned int r0 = f2bf(a.x), r1 = f2bf(a.y), r2 = f2bf(a.z), r3 = f2bf(a.w);
    unsigned int r4 = f2bf(b.x), r5 = f2bf(b.y), r6 = f2bf(b.z), r7 = f2bf(b.w);
    uint4 o;
    o.x = r0 | (r1 << 16);
    o.y = r2 | (r3 << 16);
    o.z = r4 | (r5 << 16);
    o.w = r6 | (r7 << 16);
    out4[t] = o;
}

// ---------------- weight transpose + bf16 ----------------
// W1 [256][128] fp32 -> W1t bf16 [128][256]
__global__ __launch_bounds__(256) void wt1_kernel(const float* __restrict__ W,
                                                  unsigned short* __restrict__ Wt) {
    int idx = blockIdx.x * 256 + threadIdx.x;   // 32768 = 128*256
    int n = idx >> 8, k = idx & 255;
    Wt[idx] = f2bf(W[k * 128 + n]);
}
// W2 [128][128] fp32 -> W2t bf16 [128][128]
__global__ __launch_bounds__(256) void wt2_kernel(const float* __restrict__ W,
                                                  unsigned short* __restrict__ Wt) {
    int idx = blockIdx.x * 256 + threadIdx.x;   // 16384 = 128*128
    int n = idx >> 7, k = idx & 127;
    Wt[idx] = f2bf(W[k * 128 + n]);
}

// ---------------- CSR build ----------------
__global__ void hist_kernel(const int* __restrict__ dst, int* __restrict__ counts) {
    int e = blockIdx.x * blockDim.x + threadIdx.x;
    if (e < E_) atomicAdd(&counts[dst[e]], 1);
}

__global__ __launch_bounds__(1024) void scan_kernel(const int* __restrict__ counts,
                                                    int* __restrict__ offsets,
                                                    int* __restrict__ cursor) {
    __shared__ int sums[1024];
    int t = threadIdx.x;
    const int chunk = (N_ + 1023) / 1024;  // 10
    int lo = t * chunk;
    int hi = min(lo + chunk, N_);
    int s = 0;
    for (int i = lo; i < hi; ++i) s += counts[i];
    sums[t] = s;
    __syncthreads();
    for (int off = 1; off < 1024; off <<= 1) {
        int add = (t >= off) ? sums[t - off] : 0;
        __syncthreads();
        sums[t] += add;
        __syncthreads();
    }
    int run = (t == 0) ? 0 : sums[t - 1];
    for (int i = lo; i < hi; ++i) {
        int c = counts[i];
        offsets[i] = run;
        cursor[i] = run;
        run += c;
    }
    if (t == 1023) offsets[N_] = run;  // == E_
}

__global__ void fill_kernel(const int* __restrict__ src, const int* __restrict__ dst,
                            int* __restrict__ cursor, int* __restrict__ srcs_sorted) {
    int e = blockIdx.x * blockDim.x + threadIdx.x;
    if (e < E_) {
        int d = dst[e];
        int pos = atomicAdd(&cursor[d], 1);
        srcs_sorted[pos] = src[e];
    }
}

// ---------------- segment-sum gather, bf16 in, fp32 accum, bf16 out ----------------
__global__ __launch_bounds__(256) void gather_bf16_kernel(
        const uint4* __restrict__ ebf4, const int* __restrict__ offsets,
        const int* __restrict__ srcs, uint4* __restrict__ nbbf4) {
    int bid = blockIdx.x;
    int xcd = bid & 7;
    int idx = bid >> 3;           // 0..1249
    int half = (idx >= 625) ? 1 : 0;
    int b = xcd * 2 + half;
    int ng = idx - half * 625;
    int n = ng * 16 + (threadIdx.x >> 4);
    int lane = threadIdx.x & 15;  // features lane*8 .. lane*8+7
    int beg = offsets[n], end = offsets[n + 1];
    const uint4* sb = ebf4 + (size_t)b * N_ * 16;
    float acc[8] = {0.f, 0.f, 0.f, 0.f, 0.f, 0.f, 0.f, 0.f};
    for (int e = beg; e < end; ++e) {
        int s = srcs[e];
        uint4 v = sb[(size_t)s * 16 + lane];
        acc[0] += __uint_as_float(v.x << 16);
        acc[1] += __uint_as_float(v.x & 0xffff0000u);
        acc[2] += __uint_as_float(v.y << 16);
        acc[3] += __uint_as_float(v.y & 0xffff0000u);
        acc[4] += __uint_as_float(v.z << 16);
        acc[5] += __uint_as_float(v.z & 0xffff0000u);
        acc[6] += __uint_as_float(v.w << 16);
        acc[7] += __uint_as_float(v.w & 0xffff0000u);
    }
    unsigned int r[8];
#pragma unroll
    for (int i = 0; i < 8; ++i) r[i] = f2bf(acc[i]);
    uint4 o;
    o.x = r[0] | (r[1] << 16);
    o.y = r[2] | (r[3] << 16);
    o.z = r[4] | (r[5] << 16);
    o.w = r[6] | (r[7] << 16);
    nbbf4[((size_t)b * N_ + n) * 16 + lane] = o;
}

// ---------------- fused MFMA MLP + mask select ----------------
// 256 threads = 4 waves, 64-row tile. Each wave: 16 rows x 128 cols output.
// ctx LDS: 64 rows x 264 bf16 (stride 528B = 132 dwords -> +4 banks/row, 2-way free).
// h (bf16, 64x128) overlaid into ctx cols 0..127 after layer 1.
// Fragments (guide §3, m89-verified C/D): A: row=l&15, k=8*(l>>4)+i (contig b128);
// B from Wt[n][k]: col=l&15, k=8*(l>>4)+i (contig b128); D: col=l&15, row=4*(l>>4)+reg.
__global__ __launch_bounds__(256, 3) void mlp_mfma_kernel(
        const uint4* __restrict__ nbbf4,  // bf16 [R][128]
        const uint4* __restrict__ ebf4,   // bf16 [R][128]
        const float* __restrict__ emb,    // fp32 [R][128] (exact passthrough)
        const int* __restrict__ mask,
        const unsigned short* __restrict__ W1t,  // bf16 [128][256]
        const unsigned short* __restrict__ W2t,  // bf16 [128][128]
        const float* __restrict__ b1, const float* __restrict__ b2,
        float* __restrict__ out) {
    __shared__ unsigned short ctxb[64 * LDC];
    int tx = threadIdx.x;
    int lane = tx & 63;
    int w = tx >> 6;            // wave 0..3
    size_t tile = (size_t)blockIdx.x * 64;

    // ---- stage ctx tile: 64 rows x 256 bf16 (cols 0..127 = nb, 128..255 = emb) ----
#pragma unroll
    for (int kk = 0; kk < 8; ++kk) {
        int q = tx + kk * 256;
        int row = q >> 5, c16 = q & 31;
        uint4 v = (c16 < 16) ? nbbf4[(tile + row) * 16 + c16]
                             : ebf4[(tile + row) * 16 + (c16 - 16)];
        *(uint4*)((char*)ctxb + row * (LDC * 2) + c16 * 16) = v;
    }
    __syncthreads();

    int l15 = lane & 15;
    int g = lane >> 4;          // 0..3
    int rowA = w * 16 + l15;    // A-frag row (both layers)

    // ---- layer 1: h = relu(ctx @ W1 + b1), K=256 ----
    f32x4 acc[8];
#pragma unroll
    for (int nt = 0; nt < 8; ++nt) acc[nt] = (f32x4){0.f, 0.f, 0.f, 0.f};
    const unsigned short* w1base = W1t + (size_t)l15 * 256 + g * 8;
#pragma unroll
    for (int ks = 0; ks < 8; ++ks) {
        bf16x8 a = *(const bf16x8*)((const char*)ctxb + rowA * (LDC * 2) + (ks * 32 + g * 8) * 2);
#pragma unroll
        for (int nt = 0; nt < 8; ++nt) {
            bf16x8 b = *(const bf16x8*)(w1base + (size_t)nt * 16 * 256 + ks * 32);
            acc[nt] = __builtin_amdgcn_mfma_f32_16x16x32_bf16(a, b, acc[nt], 0, 0, 0);
        }
    }
    __syncthreads();  // all ctx reads done before h overlay

    // h -> bf16 -> LDS overlay (cols 0..127)
#pragma unroll
    for (int nt = 0; nt < 8; ++nt) {
        float bv = b1[nt * 16 + l15];
#pragma unroll
        for (int r = 0; r < 4; ++r) {
            int hr = w * 16 + g * 4 + r;
            float hv = fmaxf(acc[nt][r] + bv, 0.f);
            ctxb[hr * LDC + nt * 16 + l15] = f2bf(hv);
        }
    }
    __syncthreads();

    // ---- layer 2: imputed = h @ W2 + b2, K=128 ----
    f32x4 acc2[8];
#pragma unroll
    for (int nt = 0; nt < 8; ++nt) acc2[nt] = (f32x4){0.f, 0.f, 0.f, 0.f};
    const unsigned short* w2base = W2t + (size_t)l15 * 128 + g * 8;
#pragma unroll
    for (int ks = 0; ks < 4; ++ks) {
        bf16x8 a = *(const bf16x8*)((const char*)ctxb + rowA * (LDC * 2) + (ks * 32 + g * 8) * 2);
#pragma unroll
        for (int nt = 0; nt < 8; ++nt) {
            bf16x8 b = *(const bf16x8*)(w2base + (size_t)nt * 16 * 128 + ks * 32);
            acc2[nt] = __builtin_amdgcn_mfma_f32_16x16x32_bf16(a, b, acc2[nt], 0, 0, 0);
        }
    }

    // ---- epilogue: out = mask ? imputed : emb (emb fp32 exact) ----
    size_t rbase = tile + w * 16 + g * 4;
    int m4[4];
#pragma unroll
    for (int r = 0; r < 4; ++r) m4[r] = mask[rbase + r];
#pragma unroll
    for (int nt = 0; nt < 8; ++nt) {
        float bv = b2[nt * 16 + l15];
#pragma unroll
        for (int r = 0; r < 4; ++r) {
            size_t row = rbase + r;
            int col = nt * 16 + l15;
            float val = acc2[nt][r] + bv;
            out[row * 128 + col] = m4[r] ? val : emb[row * 128 + col];
        }
    }
}

extern "C" void kernel_launch(void* const* d_in, const int* in_sizes, int n_in,
                              void* d_out, int out_size, void* d_ws, size_t ws_size,
                              hipStream_t stream) {
    const float* emb  = (const float*)d_in[0];   // (B,N,H) f32
    const int*   mask = (const int*)d_in[1];     // (B,N) i32
    const int*   eidx = (const int*)d_in[2];     // (2,E) i32
    const float* W1   = (const float*)d_in[3];   // (256,128)
    const float* b1   = (const float*)d_in[4];   // (128)
    const float* W2   = (const float*)d_in[5];   // (128,128)
    const float* b2   = (const float*)d_in[6];   // (128)
    float* out = (float*)d_out;

    const int* src = eidx;
    const int* dst = eidx + E_;

    char* ws = (char*)d_ws;
    size_t o = 0;
    unsigned short* nbbf = (unsigned short*)(ws + o); o += (size_t)R_ * H_ * 2;  // 40.96 MB
    unsigned short* ebf  = (unsigned short*)(ws + o); o += (size_t)R_ * H_ * 2;  // 40.96 MB
    unsigned short* W1t  = (unsigned short*)(ws + o); o += 128 * 256 * 2;        // 64 KB
    unsigned short* W2t  = (unsigned short*)(ws + o); o += 128 * 128 * 2;        // 32 KB
    int* counts  = (int*)(ws + o);  o += 40064;
    int* offsets = (int*)(ws + o);  o += 40064;
    int* cursor  = (int*)(ws + o);  o += 40064;
    int* srcs    = (int*)(ws + o);                   // E ints

    hipMemsetAsync(counts, 0, N_ * sizeof(int), stream);
    cvt_bf16_kernel<<<R_ * H_ / (256 * 8), 256, 0, stream>>>(
        (const float4*)emb, (uint4*)ebf);
    wt1_kernel<<<128, 256, 0, stream>>>(W1, W1t);
    wt2_kernel<<<64, 256, 0, stream>>>(W2, W2t);
    hist_kernel<<<E_ / 256, 256, 0, stream>>>(dst, counts);
    scan_kernel<<<1, 1024, 0, stream>>>(counts, offsets, cursor);
    fill_kernel<<<E_ / 256, 256, 0, stream>>>(src, dst, cursor, srcs);
    gather_bf16_kernel<<<B_ * N_ / 16, 256, 0, stream>>>(
        (const uint4*)ebf, offsets, srcs, (uint4*)nbbf);
    mlp_mfma_kernel<<<R_ / 64, 256, 0, stream>>>(
        (const uint4*)nbbf, (const uint4*)ebf, emb, mask, W1t, W2t, b1, b2, out);
}

// Round 6
// 415.105 us; speedup vs baseline: 1.7828x; 1.1462x over previous
//
#include <hip/hip_runtime.h>

#define B_ 16
#define N_ 10000
#define H_ 128
#define E_ 320000
#define R_ (B_ * N_)   // 160000 rows
#define LDC 264        // ctx LDS row stride in bf16 units (256 data + 8 pad)
#define NM_PAD 64

typedef __attribute__((ext_vector_type(8))) short bf16x8;
typedef __attribute__((ext_vector_type(4))) float f32x4;

static __device__ __forceinline__ unsigned short f2bf(float f) {
    unsigned int u = __float_as_uint(f);
    return (unsigned short)((u + 0x7fffu + ((u >> 16) & 1u)) >> 16);
}

// ---------------- fp32 -> bf16 (RNE) of node_embeddings ----------------
__global__ __launch_bounds__(256) void cvt_bf16_kernel(const float4* __restrict__ in4,
                                                       uint4* __restrict__ out4) {
    int t = blockIdx.x * 256 + threadIdx.x;      // 8 floats per thread
    float4 a = in4[t * 2 + 0];
    float4 b = in4[t * 2 + 1];
    unsigned int r0 = f2bf(a.x), r1 = f2bf(a.y), r2 = f2bf(a.z), r3 = f2bf(a.w);
    unsigned int r4 = f2bf(b.x), r5 = f2bf(b.y), r6 = f2bf(b.z), r7 = f2bf(b.w);
    uint4 o;
    o.x = r0 | (r1 << 16);
    o.y = r2 | (r3 << 16);
    o.z = r4 | (r5 << 16);
    o.w = r6 | (r7 << 16);
    out4[t] = o;
}

// ---------------- weight transpose + bf16 ----------------
__global__ __launch_bounds__(256) void wt1_kernel(const float* __restrict__ W,
                                                  unsigned short* __restrict__ Wt) {
    int idx = blockIdx.x * 256 + threadIdx.x;   // 32768 = 128*256
    int n = idx >> 8, k = idx & 255;
    Wt[idx] = f2bf(W[k * 128 + n]);             // Wt[n][k] bf16
}
__global__ __launch_bounds__(256) void wt2_kernel(const float* __restrict__ W,
                                                  unsigned short* __restrict__ Wt) {
    int idx = blockIdx.x * 256 + threadIdx.x;   // 16384 = 128*128
    int n = idx >> 7, k = idx & 127;
    Wt[idx] = f2bf(W[k * 128 + n]);
}

// ---------------- CSR build ----------------
__global__ void hist_kernel(const int* __restrict__ dst, int* __restrict__ counts) {
    int e = blockIdx.x * blockDim.x + threadIdx.x;
    if (e < E_) atomicAdd(&counts[dst[e]], 1);
}

__global__ __launch_bounds__(1024) void scan_kernel(const int* __restrict__ counts,
                                                    int* __restrict__ offsets,
                                                    int* __restrict__ cursor) {
    __shared__ int sums[1024];
    int t = threadIdx.x;
    const int chunk = (N_ + 1023) / 1024;  // 10
    int lo = t * chunk;
    int hi = min(lo + chunk, N_);
    int s = 0;
    for (int i = lo; i < hi; ++i) s += counts[i];
    sums[t] = s;
    __syncthreads();
    for (int off = 1; off < 1024; off <<= 1) {
        int add = (t >= off) ? sums[t - off] : 0;
        __syncthreads();
        sums[t] += add;
        __syncthreads();
    }
    int run = (t == 0) ? 0 : sums[t - 1];
    for (int i = lo; i < hi; ++i) {
        int c = counts[i];
        offsets[i] = run;
        cursor[i] = run;
        run += c;
    }
    if (t == 1023) offsets[N_] = run;  // == E_
}

__global__ void fill_kernel(const int* __restrict__ src, const int* __restrict__ dst,
                            int* __restrict__ cursor, int* __restrict__ srcs_sorted) {
    int e = blockIdx.x * blockDim.x + threadIdx.x;
    if (e < E_) {
        int d = dst[e];
        int pos = atomicAdd(&cursor[d], 1);
        srcs_sorted[pos] = src[e];
    }
}

// ---------------- masked-row compaction (deterministic ordered scan) ----------------
// A: per-block popcount of mask (625 blocks x 256 = 160000 exactly)
__global__ __launch_bounds__(256) void mcount_kernel(const int* __restrict__ mask,
                                                     int* __restrict__ blk_cnt) {
    int e = blockIdx.x * 256 + threadIdx.x;
    unsigned long long bal = __ballot(mask[e] != 0);
    __shared__ int wc[4];
    int wv = threadIdx.x >> 6;
    if ((threadIdx.x & 63) == 0) wc[wv] = __popcll(bal);
    __syncthreads();
    if (threadIdx.x == 0) blk_cnt[blockIdx.x] = wc[0] + wc[1] + wc[2] + wc[3];
}

// B: scan 625 block counts -> exclusive offsets, total nm, zero the pad rows
__global__ __launch_bounds__(1024) void mscan_kernel(const int* __restrict__ blk_cnt,
                                                     int* __restrict__ blk_off,
                                                     int* __restrict__ nmbuf,
                                                     int* __restrict__ rows) {
    __shared__ int s[1024];
    int t = threadIdx.x;
    int v = (t < 625) ? blk_cnt[t] : 0;
    s[t] = v;
    __syncthreads();
    for (int off = 1; off < 1024; off <<= 1) {
        int add = (t >= off) ? s[t - off] : 0;
        __syncthreads();
        s[t] += add;
        __syncthreads();
    }
    if (t < 625) blk_off[t] = s[t] - v;   // exclusive
    int nm = s[1023];
    if (t == 0) nmbuf[0] = nm;
    if (t < NM_PAD) rows[nm + t] = 0;     // pad rows -> row 0 (stores gated by i<nm)
}

// C: ordered scatter of masked row indices
__global__ __launch_bounds__(256) void mscatter_kernel(const int* __restrict__ mask,
                                                       const int* __restrict__ blk_off,
                                                       int* __restrict__ rows) {
    int e = blockIdx.x * 256 + threadIdx.x;
    int m = (mask[e] != 0);
    unsigned long long bal = __ballot(m);
    int lane = threadIdx.x & 63;
    int wv = threadIdx.x >> 6;
    __shared__ int wcnt[4];
    if (lane == 0) wcnt[wv] = __popcll(bal);
    __syncthreads();
    int woff = 0;
    for (int i = 0; i < wv; ++i) woff += wcnt[i];
    int rank = __popcll(bal & ((1ull << lane) - 1ull));
    if (m) rows[blk_off[blockIdx.x] + woff + rank] = e;
}

// ---------------- gather for masked rows only; bf16 in, fp32 accum, bf16 out ----
// 16 rows/block, grid 10000 (worst case). Bijective XCD swizzle (10000 = 8*1250):
// each XCD gets a contiguous i-chunk -> per-batch 2.56MB ebf slice stays L2-hot.
__global__ __launch_bounds__(256) void gather_c_kernel(
        const uint4* __restrict__ ebf4, const int* __restrict__ offsets,
        const int* __restrict__ srcs, const int* __restrict__ rows,
        const int* __restrict__ nmbuf, uint4* __restrict__ nbc4) {
    int bid = blockIdx.x;
    int lb = (bid & 7) * 1250 + (bid >> 3);     // logical block
    int i = lb * 16 + (threadIdx.x >> 4);
    if (i >= nmbuf[0]) return;
    int r = rows[i];
    int b = r / N_;
    int n = r - b * N_;
    int lane = threadIdx.x & 15;                // features lane*8..lane*8+7
    int beg = offsets[n], end = offsets[n + 1];
    const uint4* sb = ebf4 + (size_t)b * N_ * 16;
    float acc[8] = {0.f, 0.f, 0.f, 0.f, 0.f, 0.f, 0.f, 0.f};
    for (int e = beg; e < end; ++e) {
        int s = srcs[e];
        uint4 v = sb[(size_t)s * 16 + lane];
        acc[0] += __uint_as_float(v.x << 16);
        acc[1] += __uint_as_float(v.x & 0xffff0000u);
        acc[2] += __uint_as_float(v.y << 16);
        acc[3] += __uint_as_float(v.y & 0xffff0000u);
        acc[4] += __uint_as_float(v.z << 16);
        acc[5] += __uint_as_float(v.z & 0xffff0000u);
        acc[6] += __uint_as_float(v.w << 16);
        acc[7] += __uint_as_float(v.w & 0xffff0000u);
    }
    unsigned int rr[8];
#pragma unroll
    for (int k = 0; k < 8; ++k) rr[k] = f2bf(acc[k]);
    uint4 o;
    o.x = rr[0] | (rr[1] << 16);
    o.y = rr[2] | (rr[3] << 16);
    o.z = rr[4] | (rr[5] << 16);
    o.w = rr[6] | (rr[7] << 16);
    nbc4[(size_t)i * 16 + lane] = o;
}

// ---------------- fused MFMA MLP on compacted rows, scatter-out ----------------
// 4 waves; wave w owns cols w*32..w*32+31 (nt=2 col-frags) x all 64 tile rows.
// W-fragment loads reused across 4 row-frags -> W1t read exactly once per block.
// ctx LDS 64x264 bf16; h overlaid into cols 0..127. out prefilled with emb by memcpy;
// only i<nm rows stored here.
__global__ __launch_bounds__(256) void mlp_mfma_kernel(
        const uint4* __restrict__ nbc4,   // bf16 [nm_pad][128] compacted neighbor
        const uint4* __restrict__ ebf4,   // bf16 [R][128]
        const int* __restrict__ rows, const int* __restrict__ nmbuf,
        const unsigned short* __restrict__ W1t,  // bf16 [128][256]
        const unsigned short* __restrict__ W2t,  // bf16 [128][128]
        const float* __restrict__ b1, const float* __restrict__ b2,
        float* __restrict__ out) {
    int nm = nmbuf[0];
    int tile = blockIdx.x * 64;
    if (tile >= nm) return;
    __shared__ unsigned short ctxb[64 * LDC];
    int tx = threadIdx.x;
    int lane = tx & 63;
    int w = tx >> 6;
    int l15 = lane & 15;
    int g = lane >> 4;

    // ---- stage ctx: cols 0..127 = compacted nb (contig), 128..255 = ebf[rows[i]] ----
#pragma unroll
    for (int kk = 0; kk < 8; ++kk) {
        int q = tx + kk * 256;
        int row = q >> 5, c16 = q & 31;
        uint4 v;
        if (c16 < 16) v = nbc4[(size_t)(tile + row) * 16 + c16];
        else          v = ebf4[(size_t)rows[tile + row] * 16 + (c16 - 16)];
        *(uint4*)((char*)ctxb + row * (LDC * 2) + c16 * 16) = v;
    }
    __syncthreads();

    // ---- layer 1: K=256, wave cols (2w..2w+1)*16 ----
    f32x4 acc[4][2];
#pragma unroll
    for (int rf = 0; rf < 4; ++rf)
#pragma unroll
        for (int nt = 0; nt < 2; ++nt) acc[rf][nt] = (f32x4){0.f, 0.f, 0.f, 0.f};
#pragma unroll
    for (int ks = 0; ks < 8; ++ks) {
        bf16x8 a[4];
#pragma unroll
        for (int rf = 0; rf < 4; ++rf)
            a[rf] = *(const bf16x8*)((const char*)ctxb + (rf * 16 + l15) * (LDC * 2) + (ks * 32 + g * 8) * 2);
#pragma unroll
        for (int nt = 0; nt < 2; ++nt) {
            bf16x8 bfrag = *(const bf16x8*)(W1t + (size_t)((2 * w + nt) * 16 + l15) * 256 + ks * 32 + g * 8);
#pragma unroll
            for (int rf = 0; rf < 4; ++rf)
                acc[rf][nt] = __builtin_amdgcn_mfma_f32_16x16x32_bf16(a[rf], bfrag, acc[rf][nt], 0, 0, 0);
        }
    }
    __syncthreads();   // all layer-1 ctx reads complete

    // ---- h = relu(acc + b1) -> bf16 overlay into ctx cols 0..127 ----
#pragma unroll
    for (int nt = 0; nt < 2; ++nt) {
        float bv = b1[(2 * w + nt) * 16 + l15];
#pragma unroll
        for (int rf = 0; rf < 4; ++rf)
#pragma unroll
            for (int reg = 0; reg < 4; ++reg) {
                int hrow = rf * 16 + 4 * g + reg;
                float hv = fmaxf(acc[rf][nt][reg] + bv, 0.f);
                ctxb[hrow * LDC + (2 * w + nt) * 16 + l15] = f2bf(hv);
            }
    }
    __syncthreads();

    // ---- layer 2: K=128 ----
    f32x4 acc2[4][2];
#pragma unroll
    for (int rf = 0; rf < 4; ++rf)
#pragma unroll
        for (int nt = 0; nt < 2; ++nt) acc2[rf][nt] = (f32x4){0.f, 0.f, 0.f, 0.f};
#pragma unroll
    for (int ks = 0; ks < 4; ++ks) {
        bf16x8 a[4];
#pragma unroll
        for (int rf = 0; rf < 4; ++rf)
            a[rf] = *(const bf16x8*)((const char*)ctxb + (rf * 16 + l15) * (LDC * 2) + (ks * 32 + g * 8) * 2);
#pragma unroll
        for (int nt = 0; nt < 2; ++nt) {
            bf16x8 bfrag = *(const bf16x8*)(W2t + (size_t)((2 * w + nt) * 16 + l15) * 128 + ks * 32 + g * 8);
#pragma unroll
            for (int rf = 0; rf < 4; ++rf)
                acc2[rf][nt] = __builtin_amdgcn_mfma_f32_16x16x32_bf16(a[rf], bfrag, acc2[rf][nt], 0, 0, 0);
        }
    }

    // ---- epilogue: scatter imputed rows (out prefilled with emb) ----
    float bv2[2];
#pragma unroll
    for (int nt = 0; nt < 2; ++nt) bv2[nt] = b2[(2 * w + nt) * 16 + l15];
#pragma unroll
    for (int rf = 0; rf < 4; ++rf)
#pragma unroll
        for (int reg = 0; reg < 4; ++reg) {
            int i = tile + rf * 16 + 4 * g + reg;
            if (i < nm) {
                size_t rb = (size_t)rows[i] * 128;
#pragma unroll
                for (int nt = 0; nt < 2; ++nt)
                    out[rb + (2 * w + nt) * 16 + l15] = acc2[rf][nt][reg] + bv2[nt];
            }
        }
}

extern "C" void kernel_launch(void* const* d_in, const int* in_sizes, int n_in,
                              void* d_out, int out_size, void* d_ws, size_t ws_size,
                              hipStream_t stream) {
    const float* emb  = (const float*)d_in[0];
    const int*   mask = (const int*)d_in[1];
    const int*   eidx = (const int*)d_in[2];
    const float* W1   = (const float*)d_in[3];
    const float* b1   = (const float*)d_in[4];
    const float* W2   = (const float*)d_in[5];
    const float* b2   = (const float*)d_in[6];
    float* out = (float*)d_out;

    const int* src = eidx;
    const int* dst = eidx + E_;

    char* ws = (char*)d_ws;
    size_t o = 0;
    unsigned short* ebf = (unsigned short*)(ws + o); o += (size_t)R_ * H_ * 2;          // 40.96 MB
    unsigned short* nbc = (unsigned short*)(ws + o); o += (size_t)(R_ + NM_PAD) * H_ * 2; // 40.98 MB
    unsigned short* W1t = (unsigned short*)(ws + o); o += 128 * 256 * 2;
    unsigned short* W2t = (unsigned short*)(ws + o); o += 128 * 128 * 2;
    int* counts  = (int*)(ws + o);  o += 40064;
    int* offsets = (int*)(ws + o);  o += 40064;
    int* cursor  = (int*)(ws + o);  o += 40064;
    int* srcs    = (int*)(ws + o);  o += (size_t)E_ * 4;
    int* rows    = (int*)(ws + o);  o += (size_t)(R_ + NM_PAD) * 4;
    int* blk_cnt = (int*)(ws + o);  o += 2560;
    int* blk_off = (int*)(ws + o);  o += 2560;
    int* nmbuf   = (int*)(ws + o);  o += 64;

    // prefill out = emb (mask=0 rows exact; mask=1 rows overwritten by mlp)
    hipMemcpyAsync(out, emb, (size_t)R_ * H_ * sizeof(float),
                   hipMemcpyDeviceToDevice, stream);

    hipMemsetAsync(counts, 0, N_ * sizeof(int), stream);
    cvt_bf16_kernel<<<R_ * H_ / (256 * 8), 256, 0, stream>>>(
        (const float4*)emb, (uint4*)ebf);
    wt1_kernel<<<128, 256, 0, stream>>>(W1, W1t);
    wt2_kernel<<<64, 256, 0, stream>>>(W2, W2t);
    hist_kernel<<<E_ / 256, 256, 0, stream>>>(dst, counts);
    scan_kernel<<<1, 1024, 0, stream>>>(counts, offsets, cursor);
    fill_kernel<<<E_ / 256, 256, 0, stream>>>(src, dst, cursor, srcs);
    mcount_kernel<<<R_ / 256, 256, 0, stream>>>(mask, blk_cnt);
    mscan_kernel<<<1, 1024, 0, stream>>>(blk_cnt, blk_off, nmbuf, rows);
    mscatter_kernel<<<R_ / 256, 256, 0, stream>>>(mask, blk_off, rows);
    gather_c_kernel<<<R_ / 16, 256, 0, stream>>>(
        (const uint4*)ebf, offsets, srcs, rows, nmbuf, (uint4*)nbc);
    mlp_mfma_kernel<<<R_ / 64, 256, 0, stream>>>(
        (const uint4*)nbc, (const uint4*)ebf, rows, nmbuf, W1t, W2t, b1, b2, out);
}

// Round 7
// 344.414 us; speedup vs baseline: 2.1487x; 1.2053x over previous
//
#include <hip/hip_runtime.h>

#define B_ 16
#define N_ 10000
#define H_ 128
#define E_ 320000
#define R_ (B_ * N_)   // 160000 rows
#define LDC 264        // ctx LDS row stride in bf16 units (256 data + 8 pad)
#define NM_PAD 64

typedef __attribute__((ext_vector_type(8))) short bf16x8;
typedef __attribute__((ext_vector_type(4))) float f32x4;

static __device__ __forceinline__ unsigned short f2bf(float f) {
    unsigned int u = __float_as_uint(f);
    return (unsigned short)((u + 0x7fffu + ((u >> 16) & 1u)) >> 16);
}

// ---------------- fused: out-prefill (unmasked rows) + fp32->bf16 of emb ----------------
// t handles 8 floats of one row (16 threads/row). ebf always written; out only
// where mask==0 (masked rows are later overwritten by the MLP scatter).
__global__ __launch_bounds__(256) void prep_kernel(const float4* __restrict__ emb4,
                                                   const int* __restrict__ mask,
                                                   float4* __restrict__ out4,
                                                   uint4* __restrict__ ebf4) {
    int t = blockIdx.x * 256 + threadIdx.x;      // 8 floats per thread
    float4 a = emb4[t * 2 + 0];
    float4 b = emb4[t * 2 + 1];
    unsigned int r0 = f2bf(a.x), r1 = f2bf(a.y), r2 = f2bf(a.z), r3 = f2bf(a.w);
    unsigned int r4 = f2bf(b.x), r5 = f2bf(b.y), r6 = f2bf(b.z), r7 = f2bf(b.w);
    uint4 o;
    o.x = r0 | (r1 << 16);
    o.y = r2 | (r3 << 16);
    o.z = r4 | (r5 << 16);
    o.w = r6 | (r7 << 16);
    ebf4[t] = o;
    int row = t >> 4;
    if (!mask[row]) {
        out4[t * 2 + 0] = a;
        out4[t * 2 + 1] = b;
    }
}

// ---------------- weight transpose + bf16 ----------------
__global__ __launch_bounds__(256) void wt1_kernel(const float* __restrict__ W,
                                                  unsigned short* __restrict__ Wt) {
    int idx = blockIdx.x * 256 + threadIdx.x;   // 32768 = 128*256
    int n = idx >> 8, k = idx & 255;
    Wt[idx] = f2bf(W[k * 128 + n]);             // Wt[n][k] bf16
}
__global__ __launch_bounds__(256) void wt2_kernel(const float* __restrict__ W,
                                                  unsigned short* __restrict__ Wt) {
    int idx = blockIdx.x * 256 + threadIdx.x;   // 16384 = 128*128
    int n = idx >> 7, k = idx & 127;
    Wt[idx] = f2bf(W[k * 128 + n]);
}

// ---------------- CSR build ----------------
__global__ void hist_kernel(const int* __restrict__ dst, int* __restrict__ counts) {
    int e = blockIdx.x * blockDim.x + threadIdx.x;
    if (e < E_) atomicAdd(&counts[dst[e]], 1);
}

__global__ __launch_bounds__(1024) void scan_kernel(const int* __restrict__ counts,
                                                    int* __restrict__ offsets,
                                                    int* __restrict__ cursor) {
    __shared__ int sums[1024];
    int t = threadIdx.x;
    const int chunk = (N_ + 1023) / 1024;  // 10
    int lo = t * chunk;
    int hi = min(lo + chunk, N_);
    int s = 0;
    for (int i = lo; i < hi; ++i) s += counts[i];
    sums[t] = s;
    __syncthreads();
    for (int off = 1; off < 1024; off <<= 1) {
        int add = (t >= off) ? sums[t - off] : 0;
        __syncthreads();
        sums[t] += add;
        __syncthreads();
    }
    int run = (t == 0) ? 0 : sums[t - 1];
    for (int i = lo; i < hi; ++i) {
        int c = counts[i];
        offsets[i] = run;
        cursor[i] = run;
        run += c;
    }
    if (t == 1023) offsets[N_] = run;  // == E_
}

__global__ void fill_kernel(const int* __restrict__ src, const int* __restrict__ dst,
                            int* __restrict__ cursor, int* __restrict__ srcs_sorted) {
    int e = blockIdx.x * blockDim.x + threadIdx.x;
    if (e < E_) {
        int d = dst[e];
        int pos = atomicAdd(&cursor[d], 1);
        srcs_sorted[pos] = src[e];
    }
}

// ---------------- masked-row compaction (deterministic ordered scan) ----------------
__global__ __launch_bounds__(256) void mcount_kernel(const int* __restrict__ mask,
                                                     int* __restrict__ blk_cnt) {
    int e = blockIdx.x * 256 + threadIdx.x;
    unsigned long long bal = __ballot(mask[e] != 0);
    __shared__ int wc[4];
    int wv = threadIdx.x >> 6;
    if ((threadIdx.x & 63) == 0) wc[wv] = __popcll(bal);
    __syncthreads();
    if (threadIdx.x == 0) blk_cnt[blockIdx.x] = wc[0] + wc[1] + wc[2] + wc[3];
}

__global__ __launch_bounds__(1024) void mscan_kernel(const int* __restrict__ blk_cnt,
                                                     int* __restrict__ blk_off,
                                                     int* __restrict__ nmbuf,
                                                     int* __restrict__ rows) {
    __shared__ int s[1024];
    int t = threadIdx.x;
    int v = (t < 625) ? blk_cnt[t] : 0;
    s[t] = v;
    __syncthreads();
    for (int off = 1; off < 1024; off <<= 1) {
        int add = (t >= off) ? s[t - off] : 0;
        __syncthreads();
        s[t] += add;
        __syncthreads();
    }
    if (t < 625) blk_off[t] = s[t] - v;   // exclusive
    int nm = s[1023];
    if (t == 0) nmbuf[0] = nm;
    if (t < NM_PAD) rows[nm + t] = 0;     // pad rows -> row 0 (stores gated by i<nm)
}

__global__ __launch_bounds__(256) void mscatter_kernel(const int* __restrict__ mask,
                                                       const int* __restrict__ blk_off,
                                                       int* __restrict__ rows) {
    int e = blockIdx.x * 256 + threadIdx.x;
    int m = (mask[e] != 0);
    unsigned long long bal = __ballot(m);
    int lane = threadIdx.x & 63;
    int wv = threadIdx.x >> 6;
    __shared__ int wcnt[4];
    if (lane == 0) wcnt[wv] = __popcll(bal);
    __syncthreads();
    int woff = 0;
    for (int i = 0; i < wv; ++i) woff += wcnt[i];
    int rank = __popcll(bal & ((1ull << lane) - 1ull));
    if (m) rows[blk_off[blockIdx.x] + woff + rank] = e;
}

// ---------------- gather for masked rows; one WAVE per row, 4-way edge-parallel ----
// 64 lanes = 16 feature-lanes (uint4 each) x 4 edge-ways. Stride-4 edge loop
// (serial chain deg/4), butterfly shfl_xor(16,32) combine, way 0 stores.
// No swizzle: round-robin spreads live blocks over all 8 XCDs evenly.
__global__ __launch_bounds__(256) void gather_c_kernel(
        const uint4* __restrict__ ebf4, const int* __restrict__ offsets,
        const int* __restrict__ srcs, const int* __restrict__ rows,
        const int* __restrict__ nmbuf, uint4* __restrict__ nbc4) {
    int i = blockIdx.x * 4 + (threadIdx.x >> 6);
    if (i >= nmbuf[0]) return;
    int r = rows[i];
    int b = r / N_;                       // const divisor -> magic mul
    int n = r - b * N_;
    int lane = threadIdx.x & 63;
    int f16 = lane & 15;                  // features f16*8 .. f16*8+7
    int way = lane >> 4;                  // 0..3
    int beg = offsets[n], end = offsets[n + 1];
    const uint4* sb = ebf4 + (size_t)b * (N_ * 16);
    float acc[8] = {0.f, 0.f, 0.f, 0.f, 0.f, 0.f, 0.f, 0.f};
    for (int e = beg + way; e < end; e += 4) {
        int s = srcs[e];
        uint4 v = sb[(size_t)s * 16 + f16];
        acc[0] += __uint_as_float(v.x << 16);
        acc[1] += __uint_as_float(v.x & 0xffff0000u);
        acc[2] += __uint_as_float(v.y << 16);
        acc[3] += __uint_as_float(v.y & 0xffff0000u);
        acc[4] += __uint_as_float(v.z << 16);
        acc[5] += __uint_as_float(v.z & 0xffff0000u);
        acc[6] += __uint_as_float(v.w << 16);
        acc[7] += __uint_as_float(v.w & 0xffff0000u);
    }
#pragma unroll
    for (int k = 0; k < 8; ++k) {
        acc[k] += __shfl_xor(acc[k], 16, 64);
        acc[k] += __shfl_xor(acc[k], 32, 64);
    }
    if (way == 0) {
        unsigned int rr[8];
#pragma unroll
        for (int k = 0; k < 8; ++k) rr[k] = f2bf(acc[k]);
        uint4 o;
        o.x = rr[0] | (rr[1] << 16);
        o.y = rr[2] | (rr[3] << 16);
        o.z = rr[4] | (rr[5] << 16);
        o.w = rr[6] | (rr[7] << 16);
        nbc4[(size_t)i * 16 + f16] = o;
    }
}

// ---------------- fused MFMA MLP on compacted rows, scatter-out ----------------
__global__ __launch_bounds__(256) void mlp_mfma_kernel(
        const uint4* __restrict__ nbc4,   // bf16 [nm_pad][128] compacted neighbor
        const uint4* __restrict__ ebf4,   // bf16 [R][128]
        const int* __restrict__ rows, const int* __restrict__ nmbuf,
        const unsigned short* __restrict__ W1t,  // bf16 [128][256]
        const unsigned short* __restrict__ W2t,  // bf16 [128][128]
        const float* __restrict__ b1, const float* __restrict__ b2,
        float* __restrict__ out) {
    int nm = nmbuf[0];
    int tile = blockIdx.x * 64;
    if (tile >= nm) return;
    __shared__ unsigned short ctxb[64 * LDC];
    int tx = threadIdx.x;
    int lane = tx & 63;
    int w = tx >> 6;
    int l15 = lane & 15;
    int g = lane >> 4;

    // ---- stage ctx: cols 0..127 = compacted nb (contig), 128..255 = ebf[rows[i]] ----
#pragma unroll
    for (int kk = 0; kk < 8; ++kk) {
        int q = tx + kk * 256;
        int row = q >> 5, c16 = q & 31;
        uint4 v;
        if (c16 < 16) v = nbc4[(size_t)(tile + row) * 16 + c16];
        else          v = ebf4[(size_t)rows[tile + row] * 16 + (c16 - 16)];
        *(uint4*)((char*)ctxb + row * (LDC * 2) + c16 * 16) = v;
    }
    __syncthreads();

    // ---- layer 1: K=256, wave cols (2w..2w+1)*16 ----
    f32x4 acc[4][2];
#pragma unroll
    for (int rf = 0; rf < 4; ++rf)
#pragma unroll
        for (int nt = 0; nt < 2; ++nt) acc[rf][nt] = (f32x4){0.f, 0.f, 0.f, 0.f};
#pragma unroll
    for (int ks = 0; ks < 8; ++ks) {
        bf16x8 a[4];
#pragma unroll
        for (int rf = 0; rf < 4; ++rf)
            a[rf] = *(const bf16x8*)((const char*)ctxb + (rf * 16 + l15) * (LDC * 2) + (ks * 32 + g * 8) * 2);
#pragma unroll
        for (int nt = 0; nt < 2; ++nt) {
            bf16x8 bfrag = *(const bf16x8*)(W1t + (size_t)((2 * w + nt) * 16 + l15) * 256 + ks * 32 + g * 8);
#pragma unroll
            for (int rf = 0; rf < 4; ++rf)
                acc[rf][nt] = __builtin_amdgcn_mfma_f32_16x16x32_bf16(a[rf], bfrag, acc[rf][nt], 0, 0, 0);
        }
    }
    __syncthreads();   // all layer-1 ctx reads complete

    // ---- h = relu(acc + b1) -> bf16 overlay into ctx cols 0..127 ----
#pragma unroll
    for (int nt = 0; nt < 2; ++nt) {
        float bv = b1[(2 * w + nt) * 16 + l15];
#pragma unroll
        for (int rf = 0; rf < 4; ++rf)
#pragma unroll
            for (int reg = 0; reg < 4; ++reg) {
                int hrow = rf * 16 + 4 * g + reg;
                float hv = fmaxf(acc[rf][nt][reg] + bv, 0.f);
                ctxb[hrow * LDC + (2 * w + nt) * 16 + l15] = f2bf(hv);
            }
    }
    __syncthreads();

    // ---- layer 2: K=128 ----
    f32x4 acc2[4][2];
#pragma unroll
    for (int rf = 0; rf < 4; ++rf)
#pragma unroll
        for (int nt = 0; nt < 2; ++nt) acc2[rf][nt] = (f32x4){0.f, 0.f, 0.f, 0.f};
#pragma unroll
    for (int ks = 0; ks < 4; ++ks) {
        bf16x8 a[4];
#pragma unroll
        for (int rf = 0; rf < 4; ++rf)
            a[rf] = *(const bf16x8*)((const char*)ctxb + (rf * 16 + l15) * (LDC * 2) + (ks * 32 + g * 8) * 2);
#pragma unroll
        for (int nt = 0; nt < 2; ++nt) {
            bf16x8 bfrag = *(const bf16x8*)(W2t + (size_t)((2 * w + nt) * 16 + l15) * 128 + ks * 32 + g * 8);
#pragma unroll
            for (int rf = 0; rf < 4; ++rf)
                acc2[rf][nt] = __builtin_amdgcn_mfma_f32_16x16x32_bf16(a[rf], bfrag, acc2[rf][nt], 0, 0, 0);
        }
    }

    // ---- epilogue: scatter imputed rows (unmasked rows prefilled by prep) ----
    float bv2[2];
#pragma unroll
    for (int nt = 0; nt < 2; ++nt) bv2[nt] = b2[(2 * w + nt) * 16 + l15];
#pragma unroll
    for (int rf = 0; rf < 4; ++rf)
#pragma unroll
        for (int reg = 0; reg < 4; ++reg) {
            int i = tile + rf * 16 + 4 * g + reg;
            if (i < nm) {
                size_t rb = (size_t)rows[i] * 128;
#pragma unroll
                for (int nt = 0; nt < 2; ++nt)
                    out[rb + (2 * w + nt) * 16 + l15] = acc2[rf][nt][reg] + bv2[nt];
            }
        }
}

extern "C" void kernel_launch(void* const* d_in, const int* in_sizes, int n_in,
                              void* d_out, int out_size, void* d_ws, size_t ws_size,
                              hipStream_t stream) {
    const float* emb  = (const float*)d_in[0];
    const int*   mask = (const int*)d_in[1];
    const int*   eidx = (const int*)d_in[2];
    const float* W1   = (const float*)d_in[3];
    const float* b1   = (const float*)d_in[4];
    const float* W2   = (const float*)d_in[5];
    const float* b2   = (const float*)d_in[6];
    float* out = (float*)d_out;

    const int* src = eidx;
    const int* dst = eidx + E_;

    char* ws = (char*)d_ws;
    size_t o = 0;
    unsigned short* ebf = (unsigned short*)(ws + o); o += (size_t)R_ * H_ * 2;            // 40.96 MB
    unsigned short* nbc = (unsigned short*)(ws + o); o += (size_t)(R_ + NM_PAD) * H_ * 2; // 40.98 MB
    unsigned short* W1t = (unsigned short*)(ws + o); o += 128 * 256 * 2;
    unsigned short* W2t = (unsigned short*)(ws + o); o += 128 * 128 * 2;
    int* counts  = (int*)(ws + o);  o += 40064;
    int* offsets = (int*)(ws + o);  o += 40064;
    int* cursor  = (int*)(ws + o);  o += 40064;
    int* srcs    = (int*)(ws + o);  o += (size_t)E_ * 4;
    int* rows    = (int*)(ws + o);  o += (size_t)(R_ + NM_PAD) * 4;
    int* blk_cnt = (int*)(ws + o);  o += 2560;
    int* blk_off = (int*)(ws + o);  o += 2560;
    int* nmbuf   = (int*)(ws + o);  o += 64;

    hipMemsetAsync(counts, 0, N_ * sizeof(int), stream);
    prep_kernel<<<R_ * H_ / (256 * 8), 256, 0, stream>>>(
        (const float4*)emb, mask, (float4*)out, (uint4*)ebf);
    wt1_kernel<<<128, 256, 0, stream>>>(W1, W1t);
    wt2_kernel<<<64, 256, 0, stream>>>(W2, W2t);
    hist_kernel<<<E_ / 256, 256, 0, stream>>>(dst, counts);
    scan_kernel<<<1, 1024, 0, stream>>>(counts, offsets, cursor);
    fill_kernel<<<E_ / 256, 256, 0, stream>>>(src, dst, cursor, srcs);
    mcount_kernel<<<R_ / 256, 256, 0, stream>>>(mask, blk_cnt);
    mscan_kernel<<<1, 1024, 0, stream>>>(blk_cnt, blk_off, nmbuf, rows);
    mscatter_kernel<<<R_ / 256, 256, 0, stream>>>(mask, blk_off, rows);
    gather_c_kernel<<<R_ / 4, 256, 0, stream>>>(
        (const uint4*)ebf, offsets, srcs, rows, nmbuf, (uint4*)nbc);
    mlp_mfma_kernel<<<R_ / 64, 256, 0, stream>>>(
        (const uint4*)nbc, (const uint4*)ebf, rows, nmbuf, W1t, W2t, b1, b2, out);
}